// Round 1
// baseline (128.550 us; speedup 1.0000x reference)
//
#include <hip/hip_runtime.h>
#include <math.h>

// Problem constants (static config)
#define NB 1024     // batches
#define NS 64       // steps S
#define NT 63       // T = S-1
#define NV 192      // N = S*3 variables
#define BW 7        // band storage width: diag + 6 subdiagonals
#define NC 314      // constraint rows: 126 fw + 62 central + 126 bw

__global__ __launch_bounds__(64, 1)
void ode_banded_solve(const float* __restrict__ coeffs,   // (B, S, 1, 1, 3)
                      const float* __restrict__ rhs,      // (B, S, 1)
                      const float* __restrict__ iv_rhs,   // (B, 2, 1, 2)
                      const float* __restrict__ steps,    // (B, T)
                      float* __restrict__ out)            // (B, S, 1, 3)
{
    const int b    = blockIdx.x;
    const int lane = threadIdx.x;

    __shared__ float band[NV * BW];   // band[j*BW + d] = AtA[j][j-d]
    __shared__ float rv[NV];
    __shared__ float stp[NT + 1];

    // ---- zero band, load steps ----
    for (int i = lane; i < NV * BW; i += 64) band[i] = 0.0f;
    if (lane < NT) stp[lane] = steps[b * NT + lane];
    __syncthreads();

    // ---- block-diagonal AetAe + init-value reg + RHS (lane = step) ----
    {
        const int st = lane;  // 0..63
        const float c0 = coeffs[b * NV + st * 3 + 0];
        const float c1 = coeffs[b * NV + st * 3 + 1];
        const float c2 = coeffs[b * NV + st * 3 + 2];
        const float r  = rhs[b * NS + st];
        const float reg = (st < 2) ? 1.0f : 0.0f;
        atomicAdd(&band[(3 * st + 0) * BW + 0], c0 * c0 + reg);
        atomicAdd(&band[(3 * st + 1) * BW + 0], c1 * c1 + reg);
        atomicAdd(&band[(3 * st + 2) * BW + 0], c2 * c2);
        atomicAdd(&band[(3 * st + 1) * BW + 1], c1 * c0);
        atomicAdd(&band[(3 * st + 2) * BW + 1], c2 * c1);
        atomicAdd(&band[(3 * st + 2) * BW + 2], c2 * c0);
        float b0 = c0 * r, b1 = c1 * r, b2v = c2 * r;
        if (st < 2) {
            b0 += iv_rhs[b * 4 + st * 2 + 0];
            b1 += iv_rhs[b * 4 + st * 2 + 1];
        }
        rv[3 * st + 0] = b0;
        rv[3 * st + 1] = b1;
        rv[3 * st + 2] = b2v;
    }

    // ---- constraint rows: accumulate A^T A into band via LDS atomics ----
    for (int t = lane; t < NC; t += 64) {
        int   cols[4];
        float vals[4];
        int   cnt;
        if (t < 126) {                      // forward Taylor
            const int st = t >> 1, i = t & 1;
            const float s = stp[st];
            if (i == 0) {
                cols[0] = 3 * st + 0; vals[0] = 1.0f;
                cols[1] = 3 * st + 1; vals[1] = s;
                cols[2] = 3 * st + 2; vals[2] = 0.5f * s * s;
                cols[3] = 3 * st + 3; vals[3] = -1.0f;
                cnt = 4;
            } else {
                cols[0] = 3 * st + 1; vals[0] = s;
                cols[1] = 3 * st + 2; vals[1] = s * s;
                cols[2] = 3 * st + 4; vals[2] = -s;
                cnt = 3;
            }
        } else if (t < 188) {               // central difference
            const int st = t - 126 + 1;     // 1..62
            const float cp = stp[st - 1] + stp[st];
            cols[0] = 3 * st - 2; vals[0] = -1.0f;
            cols[1] = 3 * st + 2; vals[1] = -cp;
            cols[2] = 3 * st + 4; vals[2] = 1.0f;
            cnt = 3;
        } else {                            // backward Taylor
            const int tt = t - 188;
            const int st = tt >> 1, i = tt & 1;
            const float s = stp[st];
            if (i == 0) {
                cols[0] = 3 * st + 0; vals[0] = -1.0f;
                cols[1] = 3 * st + 3; vals[1] = 1.0f;
                cols[2] = 3 * st + 4; vals[2] = -s;
                cols[3] = 3 * st + 5; vals[3] = 0.5f * s * s;
                cnt = 4;
            } else {
                cols[0] = 3 * st + 1; vals[0] = s;
                cols[1] = 3 * st + 4; vals[1] = -s;
                cols[2] = 3 * st + 5; vals[2] = s * s;
                cnt = 3;
            }
        }
        for (int a = 0; a < cnt; ++a)
            for (int b2 = 0; b2 <= a; ++b2)
                atomicAdd(&band[cols[a] * BW + (cols[a] - cols[b2])],
                          vals[a] * vals[b2]);
    }
    __syncthreads();

    // ---- pair decode for rank-1 trailing update: lanes 0..20 -> (pa,pb), 1<=pb<=pa<=6 ----
    int pa = 0, pb = 0;
    {
        int idx = 0;
        for (int aa = 1; aa <= 6; ++aa)
            for (int bb = 1; bb <= aa; ++bb) {
                if (idx == lane) { pa = aa; pb = bb; }
                ++idx;
            }
    }
    const int sk = lane - 20;   // lanes 21..26 scale column entries k=1..6

    // ---- banded Cholesky (right-looking, deferred scaling) ----
    for (int j = 0; j < NV; ++j) {
        const int m = (NV - 1 - j < 6) ? (NV - 1 - j) : 6;
        const float diag = band[j * BW];        // fully updated by prior iters
        const float d    = sqrtf(diag);
        const float dinv = 1.0f / d;

        const bool doU = (lane < 21) && (pa <= m);
        const bool doS = (lane >= 21) && (lane <= 26) && (sk <= m);
        float ca = 0.0f, cb = 0.0f, cs = 0.0f;
        if (doU) { ca = band[(j + pa) * BW + pa]; cb = band[(j + pb) * BW + pb]; }
        if (doS) { cs = band[(j + sk) * BW + sk]; }
        __syncthreads();   // all raw reads done before any write

        if (lane == 0) band[j * BW] = d;                                  // store L[j][j]
        if (doU) band[(j + pa) * BW + (pa - pb)] -= ca * cb * (dinv * dinv);
        if (doS) band[(j + sk) * BW + sk] = cs * dinv;                    // store L[j+k][j]
        __syncthreads();
    }

    // ---- forward solve L y = rv (right-looking) ----
    for (int j = 0; j < NV; ++j) {
        const int m = (NV - 1 - j < 6) ? (NV - 1 - j) : 6;
        const float yj = rv[j] / band[j * BW];
        const bool doK = (lane >= 1) && (lane <= m);
        float sub = 0.0f, rj = 0.0f;
        if (doK) { sub = band[(j + lane) * BW + lane] * yj; rj = rv[j + lane]; }
        __syncthreads();
        if (lane == 0) rv[j] = yj;
        if (doK) rv[j + lane] = rj - sub;
        __syncthreads();
    }

    // ---- back solve L^T x = y (right-looking) ----
    for (int j = NV - 1; j >= 0; --j) {
        const int m = (j < 6) ? j : 6;
        const float xj = rv[j] / band[j * BW];
        const bool doK = (lane >= 1) && (lane <= m);
        float sub = 0.0f, rj = 0.0f;
        if (doK) { sub = band[j * BW + lane] * xj; rj = rv[j - lane]; }
        __syncthreads();
        if (lane == 0) rv[j] = xj;
        if (doK) rv[j - lane] = rj - sub;
        __syncthreads();
    }

    // ---- write output ----
    for (int i = lane; i < NV; i += 64)
        out[b * NV + i] = rv[i];
}

extern "C" void kernel_launch(void* const* d_in, const int* in_sizes, int n_in,
                              void* d_out, int out_size, void* d_ws, size_t ws_size,
                              hipStream_t stream)
{
    const float* coeffs = (const float*)d_in[0];   // 1024*64*3
    const float* rhs    = (const float*)d_in[1];   // 1024*64
    const float* iv_rhs = (const float*)d_in[2];   // 1024*2*2
    const float* steps  = (const float*)d_in[3];   // 1024*63
    float* out = (float*)d_out;                    // 1024*192

    ode_banded_solve<<<dim3(NB), dim3(64), 0, stream>>>(coeffs, rhs, iv_rhs, steps, out);
}